// Round 2
// baseline (221.684 us; speedup 1.0000x reference)
//
#include <hip/hip_runtime.h>

#define NB 4
#define NL 1024
#define NH 8
#define ND 64
#define NBH 32   // NB*NH

typedef __attribute__((ext_vector_type(8))) short bhalf8;
typedef __attribute__((ext_vector_type(4))) float f32x4;
typedef __attribute__((ext_vector_type(4))) unsigned short u16x4;

static __device__ inline unsigned short f2bf(float f) {
    union { float f; unsigned u; } x; x.f = f;
    unsigned r = x.u + 0x7FFFu + ((x.u >> 16) & 1u);   // round-nearest-even
    return (unsigned short)(r >> 16);
}

// ---------------------------------------------------------------------------
// Prep kernel (merged): blocks [0,2048) = L2-normalize q,k -> bf16 head-major;
// blocks [2048,2560) = v transpose [B,L,H,D] fp32 -> [B,H,D,L] bf16.
// 256 threads everywhere; branch is block-uniform.
// Raw q/k/v are single-use -> non-temporal loads (keep L2 for qn/kn/vt).
// ---------------------------------------------------------------------------
__global__ __launch_bounds__(256) void prep_kernel(const float* __restrict__ q,
                                                   const float* __restrict__ k,
                                                   const float* __restrict__ v,
                                                   unsigned short* __restrict__ qn,
                                                   unsigned short* __restrict__ kn,
                                                   unsigned short* __restrict__ vt) {
    int tid = threadIdx.x;
    if (blockIdx.x < 2048) {
        // ---- norm: 16 rows per block, 4 per wave, float4 I/O ----
        int w = tid >> 6, lane = tid & 63;
        int rowg = blockIdx.x * 16 + w * 4 + (lane >> 4);  // (b,l,h) row, 0..32767
        int c = lane & 15;
        f32x4 q4 = __builtin_nontemporal_load((const f32x4*)q + (size_t)rowg * 16 + c);
        f32x4 k4 = __builtin_nontemporal_load((const f32x4*)k + (size_t)rowg * 16 + c);
        float qs = q4[0]*q4[0] + q4[1]*q4[1] + q4[2]*q4[2] + q4[3]*q4[3];
        float ks = k4[0]*k4[0] + k4[1]*k4[1] + k4[2]*k4[2] + k4[3]*k4[3];
        #pragma unroll
        for (int m = 1; m < 16; m <<= 1) {
            qs += __shfl_xor(qs, m);
            ks += __shfl_xor(ks, m);
        }
        // fold 1/TEMPERATURE and 1/ln(2) into q: softmax(x/8) == softmax2(x/(8 ln2))
        float qd = 1.0f / (fmaxf(sqrtf(qs), 1e-8f) * 5.545177444479562f);
        float kd = 1.0f / fmaxf(sqrtf(ks), 1e-8f);
        int b = rowg >> 13, l = (rowg >> 3) & (NL - 1), h = rowg & (NH - 1);
        size_t o = ((size_t)(b * NH + h) * NL + l) * 16 + c;   // u16x4 units
        u16x4 qo, ko;
        qo[0] = f2bf(q4[0] * qd); qo[1] = f2bf(q4[1] * qd);
        qo[2] = f2bf(q4[2] * qd); qo[3] = f2bf(q4[3] * qd);
        ko[0] = f2bf(k4[0] * kd); ko[1] = f2bf(k4[1] * kd);
        ko[2] = f2bf(k4[2] * kd); ko[3] = f2bf(k4[3] * kd);
        ((u16x4*)qn)[o] = qo;
        ((u16x4*)kn)[o] = ko;
    } else {
        // ---- v transpose: 64l x 64d tile via bf16 LDS, vectorized both sides ----
        __shared__ unsigned short tile_t[64 * 68];   // [d][l], pad 4
        int bid = blockIdx.x - 2048;
        int bh = bid >> 4;
        int b = bh >> 3, h = bh & 7;
        int l0 = (bid & 15) * 64;
        #pragma unroll
        for (int i = 0; i < 4; ++i) {
            int l = (tid >> 4) + i * 16;
            int c4 = tid & 15;
            f32x4 vv = __builtin_nontemporal_load(
                (const f32x4*)v + (((size_t)b * NL + l0 + l) * NH + h) * 16 + c4);
            tile_t[(c4 * 4 + 0) * 68 + l] = f2bf(vv[0]);
            tile_t[(c4 * 4 + 1) * 68 + l] = f2bf(vv[1]);
            tile_t[(c4 * 4 + 2) * 68 + l] = f2bf(vv[2]);
            tile_t[(c4 * 4 + 3) * 68 + l] = f2bf(vv[3]);
        }
        __syncthreads();
        int d = tid >> 2, lg = tid & 3;
        #pragma unroll
        for (int i = 0; i < 4; ++i) {
            u16x4 u4 = *(const u16x4*)&tile_t[d * 68 + i * 16 + lg * 4];
            ((u16x4*)vt)[((size_t)(bh * ND + d)) * (NL / 4) + l0 / 4 + i * 4 + lg] = u4;
        }
    }
}

// ---------------------------------------------------------------------------
// Attention kernel: grid (NBH, NL/16) = (32,64), block 256 (4 waves).
// Block owns 16 query rows; waves split keys (256 each). SINGLE PASS over K:
// the wave's 16x256 exp-score tile lives in VGPRs (s[16] f32x4 = 64 regs).
// __launch_bounds__(256,4): cap VGPR at 128 -> >=4 waves/SIMD (latency hiding).
// attn/out stores are non-temporal: pure streaming output, keeps K/V in L2.
// ---------------------------------------------------------------------------
__global__ __launch_bounds__(256, 4) void attn_kernel(const unsigned short* __restrict__ qn,
                                                      const unsigned short* __restrict__ kn,
                                                      const unsigned short* __restrict__ vt,
                                                      float* __restrict__ outp,
                                                      float* __restrict__ attnp) {
    __shared__ __align__(16) unsigned char smem_raw[4 * 16 * 66 * 4];  // 16896 B
    __shared__ float dred[4][16];
    __shared__ float invd[16];

    unsigned short* ptile = (unsigned short*)smem_raw;  // [4][16*40] during PV
    float*          oaccf = (float*)smem_raw;           // [4][16*66] in epilogue

    int bh   = blockIdx.x;
    int wid  = threadIdx.x >> 6;             // wave -> key-range owner
    int lane = threadIdx.x & 63;
    int c    = lane & 15;
    int quad = lane >> 4;
    int m0   = blockIdx.y * 16;

    unsigned short* myp = ptile + wid * (16 * 40);

    // A-frag of Q: lane holds A[m=c][k=quad*8+j]
    const unsigned short* qbase = qn + ((size_t)(bh * NL + m0 + c)) * ND + quad * 8;
    bhalf8 qa0 = *(const bhalf8*)(qbase);
    bhalf8 qa1 = *(const bhalf8*)(qbase + 32);

    const unsigned short* kbh = kn + (size_t)bh * NL * ND;

    // ---- pass 1: scores -> exp2, kept in registers; accumulate denominator ----
    f32x4 s[16];
    float denom[4] = {0.f, 0.f, 0.f, 0.f};
    #pragma unroll
    for (int jt = 0; jt < 16; ++jt) {
        int j0 = wid * 256 + jt * 16;
        const unsigned short* kb = kbh + ((size_t)(j0 + c)) * ND + quad * 8;
        bhalf8 kf0 = *(const bhalf8*)(kb);
        bhalf8 kf1 = *(const bhalf8*)(kb + 32);
        f32x4 acc = {0.f, 0.f, 0.f, 0.f};
        acc = __builtin_amdgcn_mfma_f32_16x16x32_bf16(qa0, kf0, acc, 0, 0, 0);
        acc = __builtin_amdgcn_mfma_f32_16x16x32_bf16(qa1, kf1, acc, 0, 0, 0);
        #pragma unroll
        for (int r = 0; r < 4; ++r) {
            float e = __builtin_amdgcn_exp2f(acc[r]);
            s[jt][r] = e;
            denom[r] += e;
        }
    }
    #pragma unroll
    for (int r = 0; r < 4; ++r) {
        float d = denom[r];
        d += __shfl_xor(d, 1);
        d += __shfl_xor(d, 2);
        d += __shfl_xor(d, 4);
        d += __shfl_xor(d, 8);               // sum over the 16 col-lanes of this quad
        denom[r] = d;
    }
    if (c == 0) {
        #pragma unroll
        for (int r = 0; r < 4; ++r) dred[wid][quad * 4 + r] = denom[r];
    }
    __syncthreads();
    if (threadIdx.x < 16) {
        invd[threadIdx.x] = 1.0f / (dred[0][threadIdx.x] + dred[1][threadIdx.x] +
                                    dred[2][threadIdx.x] + dred[3][threadIdx.x]);
    }
    __syncthreads();
    float inv[4];
    #pragma unroll
    for (int r = 0; r < 4; ++r) inv[r] = invd[quad * 4 + r];

    // ---- pass 2: normalize from registers, write attn (streaming), PV ----
    float* attnrow = attnp + ((size_t)(bh * NL + m0)) * NL;
    const unsigned short* vbh = vt + (size_t)bh * ND * NL;

    f32x4 o[4] = {{0.f,0.f,0.f,0.f},{0.f,0.f,0.f,0.f},{0.f,0.f,0.f,0.f},{0.f,0.f,0.f,0.f}};
    #pragma unroll
    for (int j2 = 0; j2 < 8; ++j2) {
        int jb = wid * 256 + j2 * 32;
        #pragma unroll
        for (int sub = 0; sub < 2; ++sub) {
            int j0 = jb + sub * 16;
            #pragma unroll
            for (int r = 0; r < 4; ++r) {
                float a = s[j2 * 2 + sub][r] * inv[r];
                __builtin_nontemporal_store(a, &attnrow[(size_t)(quad * 4 + r) * NL + j0 + c]);
                myp[(quad * 4 + r) * 40 + sub * 16 + c] = f2bf(a);
            }
        }
        // C-layout -> A-layout round trip (same-wave LDS r/w)
        bhalf8 pa = *(const bhalf8*)(myp + c * 40 + quad * 8);
        #pragma unroll
        for (int nt = 0; nt < 4; ++nt) {
            const unsigned short* vb = vbh + (size_t)(nt * 16 + c) * NL + jb + quad * 8;
            bhalf8 vf = *(const bhalf8*)(vb);
            o[nt] = __builtin_amdgcn_mfma_f32_16x16x32_bf16(pa, vf, o[nt], 0, 0, 0);
        }
    }

    // ---- block-reduce O across the 4 waves (LDS aliases the P-tiles) ----
    __syncthreads();                         // all waves done reading their P-tile
    #pragma unroll
    for (int nt = 0; nt < 4; ++nt) {
        #pragma unroll
        for (int r = 0; r < 4; ++r) {
            oaccf[wid * 1056 + (quad * 4 + r) * 66 + nt * 16 + c] = o[nt][r];
        }
    }
    __syncthreads();
    float* obase = outp + ((size_t)(bh * NL + m0)) * ND;
    #pragma unroll
    for (int i = 0; i < 4; ++i) {
        int e = i * 256 + threadIdx.x;
        int row = e >> 6, col = e & 63;
        float sum = oaccf[row * 66 + col] + oaccf[1056 + row * 66 + col] +
                    oaccf[2112 + row * 66 + col] + oaccf[3168 + row * 66 + col];
        __builtin_nontemporal_store(sum, &obase[e]);
    }
}

// ---------------------------------------------------------------------------
extern "C" void kernel_launch(void* const* d_in, const int* in_sizes, int n_in,
                              void* d_out, int out_size, void* d_ws, size_t ws_size,
                              hipStream_t stream) {
    const float* q = (const float*)d_in[0];
    const float* k = (const float*)d_in[1];
    const float* v = (const float*)d_in[2];

    float* outp  = (float*)d_out;                              // [B,H,L,D] = 2M fp32
    float* attnp = outp + (size_t)NB * NH * NL * ND;           // [B,H,L,L] = 33.5M fp32

    unsigned short* qn = (unsigned short*)d_ws;                // 2M bf16
    unsigned short* kn = qn + (size_t)NB * NH * NL * ND;       // 2M bf16
    unsigned short* vt = kn + (size_t)NB * NH * NL * ND;       // 2M bf16

    prep_kernel<<<2048 + 512, 256, 0, stream>>>(q, k, v, qn, kn, vt);
    attn_kernel<<<dim3(NBH, NL / 16), 256, 0, stream>>>(qn, kn, vt, outp, attnp);
}

// Round 3
// 211.583 us; speedup vs baseline: 1.0477x; 1.0477x over previous
//
#include <hip/hip_runtime.h>

#define NB 4
#define NL 1024
#define NH 8
#define ND 64
#define NBH 32   // NB*NH

typedef __attribute__((ext_vector_type(8))) short bhalf8;
typedef __attribute__((ext_vector_type(4))) float f32x4;
typedef __attribute__((ext_vector_type(4))) unsigned short u16x4;

static __device__ inline unsigned short f2bf(float f) {
    union { float f; unsigned u; } x; x.f = f;
    unsigned r = x.u + 0x7FFFu + ((x.u >> 16) & 1u);   // round-nearest-even
    return (unsigned short)(r >> 16);
}

// ---------------------------------------------------------------------------
// Prep kernel (merged): blocks [0,2048) = L2-normalize q,k -> bf16 head-major;
// blocks [2048,2560) = v transpose [B,L,H,D] fp32 -> [B,H,D,L] bf16.
// 256 threads everywhere; branch is block-uniform.
// Raw q/k/v are single-use -> non-temporal loads (keep L2 for qn/kn/vt).
// ---------------------------------------------------------------------------
__global__ __launch_bounds__(256) void prep_kernel(const float* __restrict__ q,
                                                   const float* __restrict__ k,
                                                   const float* __restrict__ v,
                                                   unsigned short* __restrict__ qn,
                                                   unsigned short* __restrict__ kn,
                                                   unsigned short* __restrict__ vt) {
    int tid = threadIdx.x;
    if (blockIdx.x < 2048) {
        // ---- norm: 16 rows per block, 4 per wave, float4 I/O ----
        int w = tid >> 6, lane = tid & 63;
        int rowg = blockIdx.x * 16 + w * 4 + (lane >> 4);  // (b,l,h) row, 0..32767
        int c = lane & 15;
        f32x4 q4 = __builtin_nontemporal_load((const f32x4*)q + (size_t)rowg * 16 + c);
        f32x4 k4 = __builtin_nontemporal_load((const f32x4*)k + (size_t)rowg * 16 + c);
        float qs = q4[0]*q4[0] + q4[1]*q4[1] + q4[2]*q4[2] + q4[3]*q4[3];
        float ks = k4[0]*k4[0] + k4[1]*k4[1] + k4[2]*k4[2] + k4[3]*k4[3];
        #pragma unroll
        for (int m = 1; m < 16; m <<= 1) {
            qs += __shfl_xor(qs, m);
            ks += __shfl_xor(ks, m);
        }
        // fold 1/TEMPERATURE and 1/ln(2) into q: softmax(x/8) == softmax2(x/(8 ln2))
        float qd = 1.0f / (fmaxf(sqrtf(qs), 1e-8f) * 5.545177444479562f);
        float kd = 1.0f / fmaxf(sqrtf(ks), 1e-8f);
        int b = rowg >> 13, l = (rowg >> 3) & (NL - 1), h = rowg & (NH - 1);
        size_t o = ((size_t)(b * NH + h) * NL + l) * 16 + c;   // u16x4 units
        u16x4 qo, ko;
        qo[0] = f2bf(q4[0] * qd); qo[1] = f2bf(q4[1] * qd);
        qo[2] = f2bf(q4[2] * qd); qo[3] = f2bf(q4[3] * qd);
        ko[0] = f2bf(k4[0] * kd); ko[1] = f2bf(k4[1] * kd);
        ko[2] = f2bf(k4[2] * kd); ko[3] = f2bf(k4[3] * kd);
        ((u16x4*)qn)[o] = qo;
        ((u16x4*)kn)[o] = ko;
    } else {
        // ---- v transpose: 64l x 64d tile via bf16 LDS, vectorized both sides ----
        __shared__ unsigned short tile_t[64 * 68];   // [d][l], pad 4
        int bid = blockIdx.x - 2048;
        int bh = bid >> 4;
        int b = bh >> 3, h = bh & 7;
        int l0 = (bid & 15) * 64;
        #pragma unroll
        for (int i = 0; i < 4; ++i) {
            int l = (tid >> 4) + i * 16;
            int c4 = tid & 15;
            f32x4 vv = __builtin_nontemporal_load(
                (const f32x4*)v + (((size_t)b * NL + l0 + l) * NH + h) * 16 + c4);
            tile_t[(c4 * 4 + 0) * 68 + l] = f2bf(vv[0]);
            tile_t[(c4 * 4 + 1) * 68 + l] = f2bf(vv[1]);
            tile_t[(c4 * 4 + 2) * 68 + l] = f2bf(vv[2]);
            tile_t[(c4 * 4 + 3) * 68 + l] = f2bf(vv[3]);
        }
        __syncthreads();
        int d = tid >> 2, lg = tid & 3;
        #pragma unroll
        for (int i = 0; i < 4; ++i) {
            u16x4 u4 = *(const u16x4*)&tile_t[d * 68 + i * 16 + lg * 4];
            ((u16x4*)vt)[((size_t)(bh * ND + d)) * (NL / 4) + l0 / 4 + i * 4 + lg] = u4;
        }
    }
}

// ---------------------------------------------------------------------------
// Attention kernel: grid (NL/16, NBH) = (64,32), block 256 (4 waves).
// blockIdx.x = m-tile (fastest-varying) so consecutively-dispatched blocks
// share one (b,h) K/V panel -> per-XCD L2 working set ~256-512 KB (was 8 MB
// with bh fastest: guaranteed thrash of the 4 MB/XCD L2).
// Block owns 16 query rows; waves split keys (256 each). SINGLE PASS over K:
// the wave's 16x256 exp-score tile lives in VGPRs (s[16] f32x4 = 64 regs).
// attn/out stores are non-temporal: pure streaming output, keeps K/V in L2.
// ---------------------------------------------------------------------------
__global__ __launch_bounds__(256) void attn_kernel(const unsigned short* __restrict__ qn,
                                                   const unsigned short* __restrict__ kn,
                                                   const unsigned short* __restrict__ vt,
                                                   float* __restrict__ outp,
                                                   float* __restrict__ attnp) {
    __shared__ __align__(16) unsigned char smem_raw[4 * 16 * 66 * 4];  // 16896 B
    __shared__ float dred[4][16];
    __shared__ float invd[16];

    unsigned short* ptile = (unsigned short*)smem_raw;  // [4][16*40] during PV
    float*          oaccf = (float*)smem_raw;           // [4][16*66] in epilogue

    int bh   = blockIdx.y;
    int wid  = threadIdx.x >> 6;             // wave -> key-range owner
    int lane = threadIdx.x & 63;
    int c    = lane & 15;
    int quad = lane >> 4;
    int m0   = blockIdx.x * 16;

    unsigned short* myp = ptile + wid * (16 * 40);

    // A-frag of Q: lane holds A[m=c][k=quad*8+j]
    const unsigned short* qbase = qn + ((size_t)(bh * NL + m0 + c)) * ND + quad * 8;
    bhalf8 qa0 = *(const bhalf8*)(qbase);
    bhalf8 qa1 = *(const bhalf8*)(qbase + 32);

    const unsigned short* kbh = kn + (size_t)bh * NL * ND;

    // ---- pass 1: scores -> exp2, kept in registers; accumulate denominator ----
    f32x4 s[16];
    float denom[4] = {0.f, 0.f, 0.f, 0.f};
    #pragma unroll
    for (int jt = 0; jt < 16; ++jt) {
        int j0 = wid * 256 + jt * 16;
        const unsigned short* kb = kbh + ((size_t)(j0 + c)) * ND + quad * 8;
        bhalf8 kf0 = *(const bhalf8*)(kb);
        bhalf8 kf1 = *(const bhalf8*)(kb + 32);
        f32x4 acc = {0.f, 0.f, 0.f, 0.f};
        acc = __builtin_amdgcn_mfma_f32_16x16x32_bf16(qa0, kf0, acc, 0, 0, 0);
        acc = __builtin_amdgcn_mfma_f32_16x16x32_bf16(qa1, kf1, acc, 0, 0, 0);
        #pragma unroll
        for (int r = 0; r < 4; ++r) {
            float e = __builtin_amdgcn_exp2f(acc[r]);
            s[jt][r] = e;
            denom[r] += e;
        }
    }
    #pragma unroll
    for (int r = 0; r < 4; ++r) {
        float d = denom[r];
        d += __shfl_xor(d, 1);
        d += __shfl_xor(d, 2);
        d += __shfl_xor(d, 4);
        d += __shfl_xor(d, 8);               // sum over the 16 col-lanes of this quad
        denom[r] = d;
    }
    if (c == 0) {
        #pragma unroll
        for (int r = 0; r < 4; ++r) dred[wid][quad * 4 + r] = denom[r];
    }
    __syncthreads();
    if (threadIdx.x < 16) {
        invd[threadIdx.x] = 1.0f / (dred[0][threadIdx.x] + dred[1][threadIdx.x] +
                                    dred[2][threadIdx.x] + dred[3][threadIdx.x]);
    }
    __syncthreads();
    float inv[4];
    #pragma unroll
    for (int r = 0; r < 4; ++r) inv[r] = invd[quad * 4 + r];

    // ---- pass 2: normalize from registers, write attn (streaming), PV ----
    float* attnrow = attnp + ((size_t)(bh * NL + m0)) * NL;
    const unsigned short* vbh = vt + (size_t)bh * ND * NL;

    f32x4 o[4] = {{0.f,0.f,0.f,0.f},{0.f,0.f,0.f,0.f},{0.f,0.f,0.f,0.f},{0.f,0.f,0.f,0.f}};
    #pragma unroll
    for (int j2 = 0; j2 < 8; ++j2) {
        int jb = wid * 256 + j2 * 32;
        #pragma unroll
        for (int sub = 0; sub < 2; ++sub) {
            int j0 = jb + sub * 16;
            #pragma unroll
            for (int r = 0; r < 4; ++r) {
                float a = s[j2 * 2 + sub][r] * inv[r];
                __builtin_nontemporal_store(a, &attnrow[(size_t)(quad * 4 + r) * NL + j0 + c]);
                myp[(quad * 4 + r) * 40 + sub * 16 + c] = f2bf(a);
            }
        }
        // C-layout -> A-layout round trip (same-wave LDS r/w)
        bhalf8 pa = *(const bhalf8*)(myp + c * 40 + quad * 8);
        #pragma unroll
        for (int nt = 0; nt < 4; ++nt) {
            const unsigned short* vb = vbh + (size_t)(nt * 16 + c) * NL + jb + quad * 8;
            bhalf8 vf = *(const bhalf8*)(vb);
            o[nt] = __builtin_amdgcn_mfma_f32_16x16x32_bf16(pa, vf, o[nt], 0, 0, 0);
        }
    }

    // ---- block-reduce O across the 4 waves (LDS aliases the P-tiles) ----
    __syncthreads();                         // all waves done reading their P-tile
    #pragma unroll
    for (int nt = 0; nt < 4; ++nt) {
        #pragma unroll
        for (int r = 0; r < 4; ++r) {
            oaccf[wid * 1056 + (quad * 4 + r) * 66 + nt * 16 + c] = o[nt][r];
        }
    }
    __syncthreads();
    float* obase = outp + ((size_t)(bh * NL + m0)) * ND;
    #pragma unroll
    for (int i = 0; i < 4; ++i) {
        int e = i * 256 + threadIdx.x;
        int row = e >> 6, col = e & 63;
        float sum = oaccf[row * 66 + col] + oaccf[1056 + row * 66 + col] +
                    oaccf[2112 + row * 66 + col] + oaccf[3168 + row * 66 + col];
        __builtin_nontemporal_store(sum, &obase[e]);
    }
}

// ---------------------------------------------------------------------------
extern "C" void kernel_launch(void* const* d_in, const int* in_sizes, int n_in,
                              void* d_out, int out_size, void* d_ws, size_t ws_size,
                              hipStream_t stream) {
    const float* q = (const float*)d_in[0];
    const float* k = (const float*)d_in[1];
    const float* v = (const float*)d_in[2];

    float* outp  = (float*)d_out;                              // [B,H,L,D] = 2M fp32
    float* attnp = outp + (size_t)NB * NH * NL * ND;           // [B,H,L,L] = 33.5M fp32

    unsigned short* qn = (unsigned short*)d_ws;                // 2M bf16
    unsigned short* kn = qn + (size_t)NB * NH * NL * ND;       // 2M bf16
    unsigned short* vt = kn + (size_t)NB * NH * NL * ND;       // 2M bf16

    prep_kernel<<<2048 + 512, 256, 0, stream>>>(q, k, v, qn, kn, vt);
    // grid.x = m-tiles (consecutive blocks share the (b,h) K/V panel in L2)
    attn_kernel<<<dim3(NL / 16, NBH), 256, 0, stream>>>(qn, kn, vt, outp, attnp);
}